// Round 11
// baseline (431.438 us; speedup 1.0000x reference)
//
#include <hip/hip_runtime.h>
#include <math.h>

// PHM adapter: down (768->192, n=4 rank-1 kron) -> gelu_new -> up (192->768).
// Round 15: TRUE 8-waves/SIMD test. r14 aimed for high TLP but the compiler
// took 104 VGPR -> still the 65-128 bracket -> still 4 waves/SIMD -> same
// 63us. Evidence now: every 63-65us variant ran at 4 waves/SIMD; the ONE
// kernel ever to beat 2.4 TB/s delivered (r2 spill run, 3.6 TB/s) ran at 64
// VGPR = 8 waves/SIMD, occupancy 36%. VGPR occupancy steps at 64/128/256,
// so the only TLP-raising point is <=64 VGPR. r2's pin spilled because that
// body wanted 124 regs; this body is lean by design: ONE token per iter (12
// data regs), NO explicit prefetch (TLP replaces it -- that's the point),
// all weights/biases in LDS, permlane broadcast (no DS round-trips).
// Natural need ~55-70 regs -> (256,8) pin should hold spill-free. Spill
// detector: WRITE_SIZE must stay ~98MB / FETCH ~49MB; if they balloon the
// pin failed and this round reverts. Grid 2048 blocks = 8 blocks/CU, all
// resident at 64 VGPR = 32 waves/CU (2x every prior attempt).
// Keeps: coalesced remap p=a*192+4*(r+16u)+j, permlane broadcast, nt stores.

#define SQ2PI 0.79788456080286535588f

typedef float vfloat4 __attribute__((ext_vector_type(4)));
typedef unsigned int vuint2 __attribute__((ext_vector_type(2)));

template<int CTRL>
__device__ __forceinline__ float ror_add(float v) {
    // v + rotate_within_16(v, CTRL)  (DPP row_ror — VALU pipe, no DS traffic)
    int s = __builtin_amdgcn_update_dpp(0, __float_as_int(v), CTRL, 0xF, 0xF, true);
    return v + __int_as_float(s);
}
__device__ __forceinline__ float reduce16(float v) {
    v = ror_add<0x121>(v);   // row_ror:1
    v = ror_add<0x122>(v);   // row_ror:2
    v = ror_add<0x124>(v);   // row_ror:4
    v = ror_add<0x128>(v);   // row_ror:8
    return v;                // every lane: sum over its 16-lane row
}

// v_permlane16_swap_b32: exchanges odd 16-lane rows of d with even rows of s.
// v_permlane32_swap_b32: exchanges rows {2,3} of d with rows {0,1} of s.
__device__ __forceinline__ void swap16(float& d, float& s) {
    vuint2 t = __builtin_amdgcn_permlane16_swap(__float_as_uint(d), __float_as_uint(s), false, false);
    d = __uint_as_float(t.x);  s = __uint_as_float(t.y);
}
__device__ __forceinline__ void swap32(float& d, float& s) {
    vuint2 t = __builtin_amdgcn_permlane32_swap(__float_as_uint(d), __float_as_uint(s), false, false);
    d = __uint_as_float(t.x);  s = __uint_as_float(t.y);
}
// After reduce16, all lanes of row a hold H_a. Broadcast all four H's to
// every lane in 3 swap instructions (VALU pipe), no cndmask needed.
__device__ __forceinline__ void bcast4(float h, float& b0, float& b1, float& b2, float& b3) {
    float y1 = h, y2 = h;
    swap16(y1, y2);                     // y1 = H[a&2], y2 = H[(a&2)|1]
    b0 = y1; b2 = y1; swap32(b0, b2);   // b0 = H0, b2 = H2 (broadcast)
    b1 = y2; b3 = y2; swap32(b1, b3);   // b1 = H1, b3 = H3 (broadcast)
}

__device__ __forceinline__ void nt_store4(float* p, const float4& v) {
    vfloat4 nv;
    nv.x = v.x; nv.y = v.y; nv.z = v.z; nv.w = v.w;
    __builtin_nontemporal_store(nv, (vfloat4*)p);
}

__global__ __launch_bounds__(256, 8)
void phm_fused(const float* __restrict__ x,
               const float* __restrict__ rule_d,
               const float* __restrict__ Wl_d,
               const float* __restrict__ Wr_d,
               const float* __restrict__ bias_d,
               const float* __restrict__ rule_u,
               const float* __restrict__ Wl_u,
               const float* __restrict__ Wr_u,
               const float* __restrict__ bias_u,
               float* __restrict__ out,
               int n_tokens)
{
    __shared__ __attribute__((aligned(16))) float sLd[768];    // W_left_d  [i][p]  i*192+p
    __shared__ __attribute__((aligned(16))) float sRu[768];    // W_right_u [i][q2] i*192+q2
    __shared__ __attribute__((aligned(16))) float sBu[768];    // bias_u
    __shared__ __attribute__((aligned(16))) float sLu[192];    // W_left_u  [i][q]  i*48+q
    __shared__ float sBd[192];                                 // bias_d
    __shared__ float sRd[192];                                 // W_right_d [i][q]  i*48+q
    __shared__ float sRuleD[64];                               // [i][a'][c] i*16+a'*4+c
    __shared__ float sRuleU[64];

    const int tid = threadIdx.x;
    for (int i = tid; i < 768; i += 256) sLd[i] = Wl_d[i];
    for (int i = tid; i < 768; i += 256) sRu[i] = Wr_u[i];
    for (int i = tid; i < 768; i += 256) sBu[i] = bias_u[i];
    if (tid < 192) {
        sLu[tid] = Wl_u[tid];
        sBd[tid] = bias_d[tid];
        sRd[tid] = Wr_d[tid];
    }
    if (tid < 64)       sRuleD[tid]     = rule_d[tid];
    else if (tid < 128) sRuleU[tid-64]  = rule_u[tid-64];

    const int lane = tid & 63;
    const int wave = tid >> 6;
    const int a    = lane >> 4;          // kron block 0..3 (also dest c)
    const int r    = lane & 15;          // slot within block
    const int off  = 192*a + 4*r;        // coalesced remap: +64u walks the block

    __syncthreads();   // the ONLY block barrier: weights staged

    const int wid     = blockIdx.x * 4 + wave;
    const int n_waves = gridDim.x * 4;   // 8192 for the bench shape

    for (int t = wid; t < n_tokens; t += n_waves) {
        // ---- load this token (3 coalesced float4; TLP hides the latency) ----
        const float* xp = x + (size_t)t * 768 + off;
        const float4 A0 = *(const float4*)(xp);
        const float4 A1 = *(const float4*)(xp + 64);
        const float4 A2 = *(const float4*)(xp + 128);

        // ---- down dots: x[a*192 + 4r+64u + j] * Wl_d[i][4r+64u + j] ----
        float s[4] = {0,0,0,0};
        #pragma unroll
        for (int i = 0; i < 4; ++i) {
            const float4 l0 = *(const float4*)&sLd[i*192 + 4*r];
            const float4 l1 = *(const float4*)&sLd[i*192 + 4*r + 64];
            const float4 l2 = *(const float4*)&sLd[i*192 + 4*r + 128];
            s[i] = fmaf(A0.x, l0.x, s[i]);  s[i] = fmaf(A0.y, l0.y, s[i]);
            s[i] = fmaf(A0.z, l0.z, s[i]);  s[i] = fmaf(A0.w, l0.w, s[i]);
            s[i] = fmaf(A1.x, l1.x, s[i]);  s[i] = fmaf(A1.y, l1.y, s[i]);
            s[i] = fmaf(A1.z, l1.z, s[i]);  s[i] = fmaf(A1.w, l1.w, s[i]);
            s[i] = fmaf(A2.x, l2.x, s[i]);  s[i] = fmaf(A2.y, l2.y, s[i]);
            s[i] = fmaf(A2.z, l2.z, s[i]);  s[i] = fmaf(A2.w, l2.w, s[i]);
        }

        // ---- 16-lane DPP reduce + permlane broadcast + rule contraction ----
        float tD[4];
        #pragma unroll
        for (int i = 0; i < 4; ++i) {
            const float rk0 = sRuleD[i*16 +  0 + a];   // rule[i][0][a]
            const float rk1 = sRuleD[i*16 +  4 + a];
            const float rk2 = sRuleD[i*16 +  8 + a];
            const float rk3 = sRuleD[i*16 + 12 + a];
            float b0, b1, b2, b3;
            bcast4(reduce16(s[i]), b0, b1, b2, b3);
            tD[i] = fmaf(b0, rk0, fmaf(b1, rk1, fmaf(b2, rk2, b3 * rk3)));
        }

        // ---- z + gelu at o = a*48 + 3r + w ----
        float g[3];
        #pragma unroll
        for (int w = 0; w < 3; ++w) {
            float z = sBd[a*48 + 3*r + w];
            #pragma unroll
            for (int i = 0; i < 4; ++i)
                z = fmaf(tD[i], sRd[i*48 + 3*r + w], z);
            const float iv = SQ2PI * fmaf(0.044715f*z, z*z, z);
            const float e  = __expf(2.0f*iv);               // tanh(y)=1-2/(e^{2y}+1)
            g[w] = 0.5f*z*(1.0f + (1.0f - 2.0f/(e + 1.0f)));
        }

        // ---- up dots + reduce + broadcast + rule contraction ----
        float tU[4];
        #pragma unroll
        for (int i = 0; i < 4; ++i) {
            const float l0 = sLu[i*48 + 3*r + 0];
            const float l1 = sLu[i*48 + 3*r + 1];
            const float l2 = sLu[i*48 + 3*r + 2];
            const float rk0 = sRuleU[i*16 +  0 + a];
            const float rk1 = sRuleU[i*16 +  4 + a];
            const float rk2 = sRuleU[i*16 +  8 + a];
            const float rk3 = sRuleU[i*16 + 12 + a];
            float a0 = g[0]*l0 + g[1]*l1 + g[2]*l2;
            float b0, b1, b2, b3;
            bcast4(reduce16(a0), b0, b1, b2, b3);
            tU[i] = fmaf(b0, rk0, fmaf(b1, rk1, fmaf(b2, rk2, b3 * rk3)));
        }

        // ---- outputs: coalesced nt stores ----
        float* op = out + (size_t)t * 768 + off;
        #pragma unroll
        for (int u = 0; u < 3; ++u) {
            float4 ov = *(const float4*)&sBu[off + 64*u];
            #pragma unroll
            for (int i = 0; i < 4; ++i) {
                const float4 ru = *(const float4*)&sRu[i*192 + 4*r + 64*u];
                ov.x = fmaf(tU[i], ru.x, ov.x);
                ov.y = fmaf(tU[i], ru.y, ov.y);
                ov.z = fmaf(tU[i], ru.z, ov.z);
                ov.w = fmaf(tU[i], ru.w, ov.w);
            }
            nt_store4(op + 64*u, ov);
        }
    }
}

extern "C" void kernel_launch(void* const* d_in, const int* in_sizes, int n_in,
                              void* d_out, int out_size, void* d_ws, size_t ws_size,
                              hipStream_t stream) {
    const float* x      = (const float*)d_in[0];
    const float* rule_d = (const float*)d_in[1];
    const float* Wl_d   = (const float*)d_in[2];
    const float* Wr_d   = (const float*)d_in[3];
    const float* bias_d = (const float*)d_in[4];
    const float* rule_u = (const float*)d_in[5];
    const float* Wl_u   = (const float*)d_in[6];
    const float* Wr_u   = (const float*)d_in[7];
    const float* bias_u = (const float*)d_in[8];
    float* out          = (float*)d_out;

    const int n_tokens = in_sizes[0] / 768;   // 32768

    // 2048 blocks = 8192 waves (8 blocks/CU, all resident at 64 VGPR);
    // 32768 tokens -> 4 tokens/wave grid-stride.
    const int blocks = (n_tokens + 15) / 16;
    phm_fused<<<dim3(blocks), dim3(256), 0, stream>>>(
        x, rule_d, Wl_d, Wr_d, bias_d, rule_u, Wl_u, Wr_u, bias_u, out, n_tokens);
}

// Round 12
// 195.872 us; speedup vs baseline: 2.2027x; 2.2027x over previous
//
#include <hip/hip_runtime.h>
#include <math.h>

// PHM adapter: down (768->192, n=4 rank-1 kron) -> gelu_new -> up (192->768).
// Round 16: DE-NT THE STORES (single-variable A/B vs the 63us round-10
// kernel). r11's (256,8) pin repeated r2's failure (VGPR pinned at 32,
// wholesale spill, 300us) -- hard occupancy pins on this body are dead. But
// it confirmed the memory system sustains 3.27 TB/s when the request stream
// differs. What every clean 63us variant shares and the fast-BW runs don't:
// NONTEMPORAL stores. Two harms: (1) nt forces all 98MB of output to HBM
// every dispatch; (2) x(100MB)+out(98MB) FITS the 256MB Infinity Cache --
// with cached stores, out goes L3-resident across the bench's repeated
// dispatches and writes are absorbed die-side. FETCH=49MB (<100MB input)
// already proves L3 absorbs half the READ stream; nt was throwing away the
// same effect on the write stream. The nt hint dates to round 1 and was
// never A/B'd. This round: round-10 kernel, ONE change -- plain float4
// stores. Keeps: one token/iter, 1-deep prefetch issued before stores,
// coalesced remap p=a*192+4*(r+16u)+j, permlane broadcast, weights in LDS,
// no min-wave hint.

#define SQ2PI 0.79788456080286535588f

typedef unsigned int vuint2 __attribute__((ext_vector_type(2)));

template<int CTRL>
__device__ __forceinline__ float ror_add(float v) {
    // v + rotate_within_16(v, CTRL)  (DPP row_ror — VALU pipe, no DS traffic)
    int s = __builtin_amdgcn_update_dpp(0, __float_as_int(v), CTRL, 0xF, 0xF, true);
    return v + __int_as_float(s);
}
__device__ __forceinline__ float reduce16(float v) {
    v = ror_add<0x121>(v);   // row_ror:1
    v = ror_add<0x122>(v);   // row_ror:2
    v = ror_add<0x124>(v);   // row_ror:4
    v = ror_add<0x128>(v);   // row_ror:8
    return v;                // every lane: sum over its 16-lane row
}

// v_permlane16_swap_b32: exchanges odd 16-lane rows of d with even rows of s.
// v_permlane32_swap_b32: exchanges rows {2,3} of d with rows {0,1} of s.
__device__ __forceinline__ void swap16(float& d, float& s) {
    vuint2 t = __builtin_amdgcn_permlane16_swap(__float_as_uint(d), __float_as_uint(s), false, false);
    d = __uint_as_float(t.x);  s = __uint_as_float(t.y);
}
__device__ __forceinline__ void swap32(float& d, float& s) {
    vuint2 t = __builtin_amdgcn_permlane32_swap(__float_as_uint(d), __float_as_uint(s), false, false);
    d = __uint_as_float(t.x);  s = __uint_as_float(t.y);
}
// After reduce16, all lanes of row a hold H_a. Broadcast all four H's to
// every lane in 3 swap instructions (VALU pipe), no cndmask needed.
__device__ __forceinline__ void bcast4(float h, float& b0, float& b1, float& b2, float& b3) {
    float y1 = h, y2 = h;
    swap16(y1, y2);                     // y1 = H[a&2], y2 = H[(a&2)|1]
    b0 = y1; b2 = y1; swap32(b0, b2);   // b0 = H0, b2 = H2 (broadcast)
    b1 = y2; b3 = y2; swap32(b1, b3);   // b1 = H1, b3 = H3 (broadcast)
}

__global__ __launch_bounds__(256)
void phm_fused(const float* __restrict__ x,
               const float* __restrict__ rule_d,
               const float* __restrict__ Wl_d,
               const float* __restrict__ Wr_d,
               const float* __restrict__ bias_d,
               const float* __restrict__ rule_u,
               const float* __restrict__ Wl_u,
               const float* __restrict__ Wr_u,
               const float* __restrict__ bias_u,
               float* __restrict__ out,
               int n_tokens)
{
    __shared__ __attribute__((aligned(16))) float sLd[768];    // W_left_d  [i][p]  i*192+p
    __shared__ __attribute__((aligned(16))) float sRu[768];    // W_right_u [i][q2] i*192+q2
    __shared__ __attribute__((aligned(16))) float sBu[768];    // bias_u
    __shared__ __attribute__((aligned(16))) float sLu[192];    // W_left_u  [i][q]  i*48+q
    __shared__ float sBd[192];                                 // bias_d
    __shared__ float sRd[192];                                 // W_right_d [i][q]  i*48+q
    __shared__ float sRuleD[64];                               // [i][a'][c] i*16+a'*4+c
    __shared__ float sRuleU[64];

    const int tid = threadIdx.x;
    for (int i = tid; i < 768; i += 256) sLd[i] = Wl_d[i];
    for (int i = tid; i < 768; i += 256) sRu[i] = Wr_u[i];
    for (int i = tid; i < 768; i += 256) sBu[i] = bias_u[i];
    if (tid < 192) {
        sLu[tid] = Wl_u[tid];
        sBd[tid] = bias_d[tid];
        sRd[tid] = Wr_d[tid];
    }
    if (tid < 64)       sRuleD[tid]     = rule_d[tid];
    else if (tid < 128) sRuleU[tid-64]  = rule_u[tid-64];

    const int lane = tid & 63;
    const int wave = tid >> 6;
    const int a    = lane >> 4;          // kron block 0..3 (also dest c)
    const int r    = lane & 15;          // slot within block
    const int off  = 192*a + 4*r;        // coalesced remap: +64u walks the block

    __syncthreads();   // the ONLY block barrier: weights staged

    const int wid     = blockIdx.x * 4 + wave;
    const int n_waves = gridDim.x * 4;   // 8192 for the bench shape

    // ---- prologue: load first token ----
    float4 A0, A1, A2;
    if (wid < n_tokens) {
        const float* xp = x + (size_t)wid * 768 + off;
        A0 = *(const float4*)(xp);
        A1 = *(const float4*)(xp + 64);
        A2 = *(const float4*)(xp + 128);
    }

    for (int t = wid; t < n_tokens; t += n_waves) {
        // ---- prefetch next token FIRST (before this token's stores) ----
        const int tn = t + n_waves;
        const float* np = x + (size_t)(tn < n_tokens ? tn : t) * 768 + off;
        float4 B0 = *(const float4*)(np);
        float4 B1 = *(const float4*)(np + 64);
        float4 B2 = *(const float4*)(np + 128);

        // ---- down dots: x[a*192 + 4r+64u + j] * Wl_d[i][4r+64u + j] ----
        float s[4] = {0,0,0,0};
        #pragma unroll
        for (int i = 0; i < 4; ++i) {
            const float4 l0 = *(const float4*)&sLd[i*192 + 4*r];
            const float4 l1 = *(const float4*)&sLd[i*192 + 4*r + 64];
            const float4 l2 = *(const float4*)&sLd[i*192 + 4*r + 128];
            s[i] = fmaf(A0.x, l0.x, s[i]);  s[i] = fmaf(A0.y, l0.y, s[i]);
            s[i] = fmaf(A0.z, l0.z, s[i]);  s[i] = fmaf(A0.w, l0.w, s[i]);
            s[i] = fmaf(A1.x, l1.x, s[i]);  s[i] = fmaf(A1.y, l1.y, s[i]);
            s[i] = fmaf(A1.z, l1.z, s[i]);  s[i] = fmaf(A1.w, l1.w, s[i]);
            s[i] = fmaf(A2.x, l2.x, s[i]);  s[i] = fmaf(A2.y, l2.y, s[i]);
            s[i] = fmaf(A2.z, l2.z, s[i]);  s[i] = fmaf(A2.w, l2.w, s[i]);
        }

        // ---- 16-lane DPP reduce + permlane broadcast + rule contraction ----
        float tD[4];
        #pragma unroll
        for (int i = 0; i < 4; ++i) {
            const float rk0 = sRuleD[i*16 +  0 + a];   // rule[i][0][a]
            const float rk1 = sRuleD[i*16 +  4 + a];
            const float rk2 = sRuleD[i*16 +  8 + a];
            const float rk3 = sRuleD[i*16 + 12 + a];
            float b0, b1, b2, b3;
            bcast4(reduce16(s[i]), b0, b1, b2, b3);
            tD[i] = fmaf(b0, rk0, fmaf(b1, rk1, fmaf(b2, rk2, b3 * rk3)));
        }

        // ---- z + gelu at o = a*48 + 3r + w ----
        float g[3];
        #pragma unroll
        for (int w = 0; w < 3; ++w) {
            float z = sBd[a*48 + 3*r + w];
            #pragma unroll
            for (int i = 0; i < 4; ++i)
                z = fmaf(tD[i], sRd[i*48 + 3*r + w], z);
            const float iv = SQ2PI * fmaf(0.044715f*z, z*z, z);
            const float e  = __expf(2.0f*iv);               // tanh(y)=1-2/(e^{2y}+1)
            g[w] = 0.5f*z*(1.0f + (1.0f - 2.0f/(e + 1.0f)));
        }

        // ---- up dots + reduce + broadcast + rule contraction ----
        float tU[4];
        #pragma unroll
        for (int i = 0; i < 4; ++i) {
            const float l0 = sLu[i*48 + 3*r + 0];
            const float l1 = sLu[i*48 + 3*r + 1];
            const float l2 = sLu[i*48 + 3*r + 2];
            const float rk0 = sRuleU[i*16 +  0 + a];
            const float rk1 = sRuleU[i*16 +  4 + a];
            const float rk2 = sRuleU[i*16 +  8 + a];
            const float rk3 = sRuleU[i*16 + 12 + a];
            float a0 = g[0]*l0 + g[1]*l1 + g[2]*l2;
            float b0, b1, b2, b3;
            bcast4(reduce16(a0), b0, b1, b2, b3);
            tU[i] = fmaf(b0, rk0, fmaf(b1, rk1, fmaf(b2, rk2, b3 * rk3)));
        }

        // ---- outputs: coalesced CACHED stores (L3 can absorb them) ----
        float* op = out + (size_t)t * 768 + off;
        #pragma unroll
        for (int u = 0; u < 3; ++u) {
            float4 ov = *(const float4*)&sBu[off + 64*u];
            #pragma unroll
            for (int i = 0; i < 4; ++i) {
                const float4 ru = *(const float4*)&sRu[i*192 + 4*r + 64*u];
                ov.x = fmaf(tU[i], ru.x, ov.x);
                ov.y = fmaf(tU[i], ru.y, ov.y);
                ov.z = fmaf(tU[i], ru.z, ov.z);
                ov.w = fmaf(tU[i], ru.w, ov.w);
            }
            *(float4*)(op + 64*u) = ov;
        }

        // ---- rotate prefetch into current ----
        A0 = B0; A1 = B1; A2 = B2;
    }
}

extern "C" void kernel_launch(void* const* d_in, const int* in_sizes, int n_in,
                              void* d_out, int out_size, void* d_ws, size_t ws_size,
                              hipStream_t stream) {
    const float* x      = (const float*)d_in[0];
    const float* rule_d = (const float*)d_in[1];
    const float* Wl_d   = (const float*)d_in[2];
    const float* Wr_d   = (const float*)d_in[3];
    const float* bias_d = (const float*)d_in[4];
    const float* rule_u = (const float*)d_in[5];
    const float* Wl_u   = (const float*)d_in[6];
    const float* Wr_u   = (const float*)d_in[7];
    const float* bias_u = (const float*)d_in[8];
    float* out          = (float*)d_out;

    const int n_tokens = in_sizes[0] / 768;   // 32768

    // 2048 blocks = 8192 waves; 32768 tokens -> 4 tokens/wave grid-stride.
    const int blocks = (n_tokens + 15) / 16;
    phm_fused<<<dim3(blocks), dim3(256), 0, stream>>>(
        x, rule_d, Wl_d, Wr_d, bias_d, rule_u, Wl_u, Wr_u, bias_u, out, n_tokens);
}

// Round 13
// 195.453 us; speedup vs baseline: 2.2074x; 1.0021x over previous
//
#include <hip/hip_runtime.h>
#include <math.h>

// PHM adapter: down (768->192, n=4 rank-1 kron) -> gelu_new -> up (192->768).
// Round 17: NATURAL <=64 VGPR (8 waves/SIMD without a pin). Surviving model:
// delivered BW tracks resident waves -- all 4-wave/SIMD variants get 2.2-2.4
// TB/s; the only runs above (r2 3.6, r11 3.3 TB/s) ran 8 waves/SIMD, even
// with pathological spill patterns. Hard pins spill (r2,r11: allocator pins
// 32-64 and dumps everything to scratch). This round shrinks the natural
// allocation instead: r10's 104 VGPR = 12 prefetch regs + LICM-hoisted
// loop-invariant LDS weight reads (sLd alone = 48 regs). Fix: (a) drop the
// explicit prefetch (TLP replaces it -- that IS the hypothesis); (b)
// asm volatile memory clobber at loop top forbids carrying weight values
// across iterations -> weights re-read from LDS each trip (DS ~6-12cy,
// 0 conflicts measured, trivially cheap) -> live set ~40-45 regs. No pin,
// so no spill failure mode; worst case allocator lands 65-80 and we match
// current perf. Keeps: coalesced remap p=a*192+4*(r+16u)+j, permlane
// broadcast, weights/biases in LDS, plain cached stores (r12: nt vs cached
// indistinguishable), 2048 blocks (8/CU -> 32 waves/CU capacity at 64 VGPR).

#define SQ2PI 0.79788456080286535588f

typedef unsigned int vuint2 __attribute__((ext_vector_type(2)));

template<int CTRL>
__device__ __forceinline__ float ror_add(float v) {
    // v + rotate_within_16(v, CTRL)  (DPP row_ror — VALU pipe, no DS traffic)
    int s = __builtin_amdgcn_update_dpp(0, __float_as_int(v), CTRL, 0xF, 0xF, true);
    return v + __int_as_float(s);
}
__device__ __forceinline__ float reduce16(float v) {
    v = ror_add<0x121>(v);   // row_ror:1
    v = ror_add<0x122>(v);   // row_ror:2
    v = ror_add<0x124>(v);   // row_ror:4
    v = ror_add<0x128>(v);   // row_ror:8
    return v;                // every lane: sum over its 16-lane row
}

// v_permlane16_swap_b32: exchanges odd 16-lane rows of d with even rows of s.
// v_permlane32_swap_b32: exchanges rows {2,3} of d with rows {0,1} of s.
__device__ __forceinline__ void swap16(float& d, float& s) {
    vuint2 t = __builtin_amdgcn_permlane16_swap(__float_as_uint(d), __float_as_uint(s), false, false);
    d = __uint_as_float(t.x);  s = __uint_as_float(t.y);
}
__device__ __forceinline__ void swap32(float& d, float& s) {
    vuint2 t = __builtin_amdgcn_permlane32_swap(__float_as_uint(d), __float_as_uint(s), false, false);
    d = __uint_as_float(t.x);  s = __uint_as_float(t.y);
}
// After reduce16, all lanes of row a hold H_a. Broadcast all four H's to
// every lane in 3 swap instructions (VALU pipe), no cndmask needed.
__device__ __forceinline__ void bcast4(float h, float& b0, float& b1, float& b2, float& b3) {
    float y1 = h, y2 = h;
    swap16(y1, y2);                     // y1 = H[a&2], y2 = H[(a&2)|1]
    b0 = y1; b2 = y1; swap32(b0, b2);   // b0 = H0, b2 = H2 (broadcast)
    b1 = y2; b3 = y2; swap32(b1, b3);   // b1 = H1, b3 = H3 (broadcast)
}

__global__ __launch_bounds__(256)
void phm_fused(const float* __restrict__ x,
               const float* __restrict__ rule_d,
               const float* __restrict__ Wl_d,
               const float* __restrict__ Wr_d,
               const float* __restrict__ bias_d,
               const float* __restrict__ rule_u,
               const float* __restrict__ Wl_u,
               const float* __restrict__ Wr_u,
               const float* __restrict__ bias_u,
               float* __restrict__ out,
               int n_tokens)
{
    __shared__ __attribute__((aligned(16))) float sLd[768];    // W_left_d  [i][p]  i*192+p
    __shared__ __attribute__((aligned(16))) float sRu[768];    // W_right_u [i][q2] i*192+q2
    __shared__ __attribute__((aligned(16))) float sBu[768];    // bias_u
    __shared__ __attribute__((aligned(16))) float sLu[192];    // W_left_u  [i][q]  i*48+q
    __shared__ float sBd[192];                                 // bias_d
    __shared__ float sRd[192];                                 // W_right_d [i][q]  i*48+q
    __shared__ float sRuleD[64];                               // [i][a'][c] i*16+a'*4+c
    __shared__ float sRuleU[64];

    const int tid = threadIdx.x;
    for (int i = tid; i < 768; i += 256) sLd[i] = Wl_d[i];
    for (int i = tid; i < 768; i += 256) sRu[i] = Wr_u[i];
    for (int i = tid; i < 768; i += 256) sBu[i] = bias_u[i];
    if (tid < 192) {
        sLu[tid] = Wl_u[tid];
        sBd[tid] = bias_d[tid];
        sRd[tid] = Wr_d[tid];
    }
    if (tid < 64)       sRuleD[tid]     = rule_d[tid];
    else if (tid < 128) sRuleU[tid-64]  = rule_u[tid-64];

    const int lane = tid & 63;
    const int wave = tid >> 6;
    const int a    = lane >> 4;          // kron block 0..3 (also dest c)
    const int r    = lane & 15;          // slot within block
    const int off  = 192*a + 4*r;        // coalesced remap: +64u walks the block

    __syncthreads();   // the ONLY block barrier: weights staged

    const int wid     = blockIdx.x * 4 + wave;
    const int n_waves = gridDim.x * 4;   // 8192 for the bench shape

    for (int t = wid; t < n_tokens; t += n_waves) {
        // Defeat LICM: weight values must NOT be carried across iterations
        // in registers -- re-read from LDS each trip (cheap) to keep the
        // live set ~40-45 VGPR -> 8 waves/SIMD bracket.
        asm volatile("" ::: "memory");

        // ---- load this token (3 coalesced float4; TLP hides the latency) ----
        const float* xp = x + (size_t)t * 768 + off;
        const float4 A0 = *(const float4*)(xp);
        const float4 A1 = *(const float4*)(xp + 64);
        const float4 A2 = *(const float4*)(xp + 128);

        // ---- down dots: x[a*192 + 4r+64u + j] * Wl_d[i][4r+64u + j] ----
        float s[4] = {0,0,0,0};
        #pragma unroll
        for (int i = 0; i < 4; ++i) {
            const float4 l0 = *(const float4*)&sLd[i*192 + 4*r];
            const float4 l1 = *(const float4*)&sLd[i*192 + 4*r + 64];
            const float4 l2 = *(const float4*)&sLd[i*192 + 4*r + 128];
            s[i] = fmaf(A0.x, l0.x, s[i]);  s[i] = fmaf(A0.y, l0.y, s[i]);
            s[i] = fmaf(A0.z, l0.z, s[i]);  s[i] = fmaf(A0.w, l0.w, s[i]);
            s[i] = fmaf(A1.x, l1.x, s[i]);  s[i] = fmaf(A1.y, l1.y, s[i]);
            s[i] = fmaf(A1.z, l1.z, s[i]);  s[i] = fmaf(A1.w, l1.w, s[i]);
            s[i] = fmaf(A2.x, l2.x, s[i]);  s[i] = fmaf(A2.y, l2.y, s[i]);
            s[i] = fmaf(A2.z, l2.z, s[i]);  s[i] = fmaf(A2.w, l2.w, s[i]);
        }

        // ---- 16-lane DPP reduce + permlane broadcast + rule contraction ----
        float tD[4];
        #pragma unroll
        for (int i = 0; i < 4; ++i) {
            const float rk0 = sRuleD[i*16 +  0 + a];   // rule[i][0][a]
            const float rk1 = sRuleD[i*16 +  4 + a];
            const float rk2 = sRuleD[i*16 +  8 + a];
            const float rk3 = sRuleD[i*16 + 12 + a];
            float b0, b1, b2, b3;
            bcast4(reduce16(s[i]), b0, b1, b2, b3);
            tD[i] = fmaf(b0, rk0, fmaf(b1, rk1, fmaf(b2, rk2, b3 * rk3)));
        }

        // ---- z + gelu at o = a*48 + 3r + w ----
        float g[3];
        #pragma unroll
        for (int w = 0; w < 3; ++w) {
            float z = sBd[a*48 + 3*r + w];
            #pragma unroll
            for (int i = 0; i < 4; ++i)
                z = fmaf(tD[i], sRd[i*48 + 3*r + w], z);
            const float iv = SQ2PI * fmaf(0.044715f*z, z*z, z);
            const float e  = __expf(2.0f*iv);               // tanh(y)=1-2/(e^{2y}+1)
            g[w] = 0.5f*z*(1.0f + (1.0f - 2.0f/(e + 1.0f)));
        }

        // ---- up dots + reduce + broadcast + rule contraction ----
        float tU[4];
        #pragma unroll
        for (int i = 0; i < 4; ++i) {
            const float l0 = sLu[i*48 + 3*r + 0];
            const float l1 = sLu[i*48 + 3*r + 1];
            const float l2 = sLu[i*48 + 3*r + 2];
            const float rk0 = sRuleU[i*16 +  0 + a];
            const float rk1 = sRuleU[i*16 +  4 + a];
            const float rk2 = sRuleU[i*16 +  8 + a];
            const float rk3 = sRuleU[i*16 + 12 + a];
            float a0 = g[0]*l0 + g[1]*l1 + g[2]*l2;
            float b0, b1, b2, b3;
            bcast4(reduce16(a0), b0, b1, b2, b3);
            tU[i] = fmaf(b0, rk0, fmaf(b1, rk1, fmaf(b2, rk2, b3 * rk3)));
        }

        // ---- outputs: coalesced cached stores, per-u to keep live set low ----
        float* op = out + (size_t)t * 768 + off;
        #pragma unroll
        for (int u = 0; u < 3; ++u) {
            float4 ov = *(const float4*)&sBu[off + 64*u];
            #pragma unroll
            for (int i = 0; i < 4; ++i) {
                const float4 ru = *(const float4*)&sRu[i*192 + 4*r + 64*u];
                ov.x = fmaf(tU[i], ru.x, ov.x);
                ov.y = fmaf(tU[i], ru.y, ov.y);
                ov.z = fmaf(tU[i], ru.z, ov.z);
                ov.w = fmaf(tU[i], ru.w, ov.w);
            }
            *(float4*)(op + 64*u) = ov;
        }
    }
}

extern "C" void kernel_launch(void* const* d_in, const int* in_sizes, int n_in,
                              void* d_out, int out_size, void* d_ws, size_t ws_size,
                              hipStream_t stream) {
    const float* x      = (const float*)d_in[0];
    const float* rule_d = (const float*)d_in[1];
    const float* Wl_d   = (const float*)d_in[2];
    const float* Wr_d   = (const float*)d_in[3];
    const float* bias_d = (const float*)d_in[4];
    const float* rule_u = (const float*)d_in[5];
    const float* Wl_u   = (const float*)d_in[6];
    const float* Wr_u   = (const float*)d_in[7];
    const float* bias_u = (const float*)d_in[8];
    float* out          = (float*)d_out;

    const int n_tokens = in_sizes[0] / 768;   // 32768

    // 2048 blocks = 8192 waves (8 blocks/CU); 32768 tokens -> 4 tokens/wave.
    const int blocks = (n_tokens + 15) / 16;
    phm_fused<<<dim3(blocks), dim3(256), 0, stream>>>(
        x, rule_d, Wl_d, Wr_d, bias_d, rule_u, Wl_u, Wr_u, bias_u, out, n_tokens);
}

// Round 14
// 194.136 us; speedup vs baseline: 2.2224x; 1.0068x over previous
//
#include <hip/hip_runtime.h>
#include <math.h>

// PHM adapter: down (768->192, n=4 rank-1 kron) -> gelu_new -> up (192->768).
// Round 18: TLP x MLP product test. r17 proved occupancy alone is not the
// lever (VGPR 36, occ 48%, 3x waves -> dur unchanged 63us), but the diet
// also REMOVED the prefetch, so in-flight product stayed constant:
//   r10: 16 waves/CU x 6 loads  ~= 96 in flight -> 2.4 TB/s
//   r17: 30 waves/CU x 3 loads  ~= 90 in flight -> 2.4 TB/s (same!)
// Spill runs (r2/r11) with huge per-wave request counts AND decent waves hit
// 3.3-3.6 TB/s. Hypothesis: BW ~ waves x outstanding-per-wave. r17 has ~28
// free VGPRs below the 64 cliff -> add back 1-deep prefetch (12 regs, loads
// for t+1 in flight across compute+store of t) => product ~180, VGPR ~50-56
// (gate: <=64). Memory clobber stays: it forbids caching LDS weight VALUES
// across iterations (LICM) but prefetched register values legitimately
// carry. Keeps: coalesced remap p=a*192+4*(r+16u)+j, permlane broadcast,
// weights/biases in LDS, cached stores, 2048 blocks, no occupancy pin
// (pins spill: r2/r11).

#define SQ2PI 0.79788456080286535588f

typedef unsigned int vuint2 __attribute__((ext_vector_type(2)));

template<int CTRL>
__device__ __forceinline__ float ror_add(float v) {
    // v + rotate_within_16(v, CTRL)  (DPP row_ror — VALU pipe, no DS traffic)
    int s = __builtin_amdgcn_update_dpp(0, __float_as_int(v), CTRL, 0xF, 0xF, true);
    return v + __int_as_float(s);
}
__device__ __forceinline__ float reduce16(float v) {
    v = ror_add<0x121>(v);   // row_ror:1
    v = ror_add<0x122>(v);   // row_ror:2
    v = ror_add<0x124>(v);   // row_ror:4
    v = ror_add<0x128>(v);   // row_ror:8
    return v;                // every lane: sum over its 16-lane row
}

// v_permlane16_swap_b32: exchanges odd 16-lane rows of d with even rows of s.
// v_permlane32_swap_b32: exchanges rows {2,3} of d with rows {0,1} of s.
__device__ __forceinline__ void swap16(float& d, float& s) {
    vuint2 t = __builtin_amdgcn_permlane16_swap(__float_as_uint(d), __float_as_uint(s), false, false);
    d = __uint_as_float(t.x);  s = __uint_as_float(t.y);
}
__device__ __forceinline__ void swap32(float& d, float& s) {
    vuint2 t = __builtin_amdgcn_permlane32_swap(__float_as_uint(d), __float_as_uint(s), false, false);
    d = __uint_as_float(t.x);  s = __uint_as_float(t.y);
}
// After reduce16, all lanes of row a hold H_a. Broadcast all four H's to
// every lane in 3 swap instructions (VALU pipe), no cndmask needed.
__device__ __forceinline__ void bcast4(float h, float& b0, float& b1, float& b2, float& b3) {
    float y1 = h, y2 = h;
    swap16(y1, y2);                     // y1 = H[a&2], y2 = H[(a&2)|1]
    b0 = y1; b2 = y1; swap32(b0, b2);   // b0 = H0, b2 = H2 (broadcast)
    b1 = y2; b3 = y2; swap32(b1, b3);   // b1 = H1, b3 = H3 (broadcast)
}

__global__ __launch_bounds__(256)
void phm_fused(const float* __restrict__ x,
               const float* __restrict__ rule_d,
               const float* __restrict__ Wl_d,
               const float* __restrict__ Wr_d,
               const float* __restrict__ bias_d,
               const float* __restrict__ rule_u,
               const float* __restrict__ Wl_u,
               const float* __restrict__ Wr_u,
               const float* __restrict__ bias_u,
               float* __restrict__ out,
               int n_tokens)
{
    __shared__ __attribute__((aligned(16))) float sLd[768];    // W_left_d  [i][p]  i*192+p
    __shared__ __attribute__((aligned(16))) float sRu[768];    // W_right_u [i][q2] i*192+q2
    __shared__ __attribute__((aligned(16))) float sBu[768];    // bias_u
    __shared__ __attribute__((aligned(16))) float sLu[192];    // W_left_u  [i][q]  i*48+q
    __shared__ float sBd[192];                                 // bias_d
    __shared__ float sRd[192];                                 // W_right_d [i][q]  i*48+q
    __shared__ float sRuleD[64];                               // [i][a'][c] i*16+a'*4+c
    __shared__ float sRuleU[64];

    const int tid = threadIdx.x;
    for (int i = tid; i < 768; i += 256) sLd[i] = Wl_d[i];
    for (int i = tid; i < 768; i += 256) sRu[i] = Wr_u[i];
    for (int i = tid; i < 768; i += 256) sBu[i] = bias_u[i];
    if (tid < 192) {
        sLu[tid] = Wl_u[tid];
        sBd[tid] = bias_d[tid];
        sRd[tid] = Wr_d[tid];
    }
    if (tid < 64)       sRuleD[tid]     = rule_d[tid];
    else if (tid < 128) sRuleU[tid-64]  = rule_u[tid-64];

    const int lane = tid & 63;
    const int wave = tid >> 6;
    const int a    = lane >> 4;          // kron block 0..3 (also dest c)
    const int r    = lane & 15;          // slot within block
    const int off  = 192*a + 4*r;        // coalesced remap: +64u walks the block

    __syncthreads();   // the ONLY block barrier: weights staged

    const int wid     = blockIdx.x * 4 + wave;
    const int n_waves = gridDim.x * 4;   // 8192 for the bench shape

    // ---- prologue: load first token ----
    float4 A0, A1, A2;
    if (wid < n_tokens) {
        const float* xp = x + (size_t)wid * 768 + off;
        A0 = *(const float4*)(xp);
        A1 = *(const float4*)(xp + 64);
        A2 = *(const float4*)(xp + 128);
    }

    for (int t = wid; t < n_tokens; t += n_waves) {
        // Defeat LICM of LDS weight values (keeps live set small); the
        // prefetched A/B register values legitimately carry across.
        asm volatile("" ::: "memory");

        // ---- issue next token's loads FIRST (in flight across compute) ----
        const int tn = t + n_waves;
        const float* np = x + (size_t)(tn < n_tokens ? tn : t) * 768 + off;
        float4 B0 = *(const float4*)(np);
        float4 B1 = *(const float4*)(np + 64);
        float4 B2 = *(const float4*)(np + 128);

        // ---- down dots: x[a*192 + 4r+64u + j] * Wl_d[i][4r+64u + j] ----
        float s[4] = {0,0,0,0};
        #pragma unroll
        for (int i = 0; i < 4; ++i) {
            const float4 l0 = *(const float4*)&sLd[i*192 + 4*r];
            const float4 l1 = *(const float4*)&sLd[i*192 + 4*r + 64];
            const float4 l2 = *(const float4*)&sLd[i*192 + 4*r + 128];
            s[i] = fmaf(A0.x, l0.x, s[i]);  s[i] = fmaf(A0.y, l0.y, s[i]);
            s[i] = fmaf(A0.z, l0.z, s[i]);  s[i] = fmaf(A0.w, l0.w, s[i]);
            s[i] = fmaf(A1.x, l1.x, s[i]);  s[i] = fmaf(A1.y, l1.y, s[i]);
            s[i] = fmaf(A1.z, l1.z, s[i]);  s[i] = fmaf(A1.w, l1.w, s[i]);
            s[i] = fmaf(A2.x, l2.x, s[i]);  s[i] = fmaf(A2.y, l2.y, s[i]);
            s[i] = fmaf(A2.z, l2.z, s[i]);  s[i] = fmaf(A2.w, l2.w, s[i]);
        }

        // ---- 16-lane DPP reduce + permlane broadcast + rule contraction ----
        float tD[4];
        #pragma unroll
        for (int i = 0; i < 4; ++i) {
            const float rk0 = sRuleD[i*16 +  0 + a];   // rule[i][0][a]
            const float rk1 = sRuleD[i*16 +  4 + a];
            const float rk2 = sRuleD[i*16 +  8 + a];
            const float rk3 = sRuleD[i*16 + 12 + a];
            float b0, b1, b2, b3;
            bcast4(reduce16(s[i]), b0, b1, b2, b3);
            tD[i] = fmaf(b0, rk0, fmaf(b1, rk1, fmaf(b2, rk2, b3 * rk3)));
        }

        // ---- z + gelu at o = a*48 + 3r + w ----
        float g[3];
        #pragma unroll
        for (int w = 0; w < 3; ++w) {
            float z = sBd[a*48 + 3*r + w];
            #pragma unroll
            for (int i = 0; i < 4; ++i)
                z = fmaf(tD[i], sRd[i*48 + 3*r + w], z);
            const float iv = SQ2PI * fmaf(0.044715f*z, z*z, z);
            const float e  = __expf(2.0f*iv);               // tanh(y)=1-2/(e^{2y}+1)
            g[w] = 0.5f*z*(1.0f + (1.0f - 2.0f/(e + 1.0f)));
        }

        // ---- up dots + reduce + broadcast + rule contraction ----
        float tU[4];
        #pragma unroll
        for (int i = 0; i < 4; ++i) {
            const float l0 = sLu[i*48 + 3*r + 0];
            const float l1 = sLu[i*48 + 3*r + 1];
            const float l2 = sLu[i*48 + 3*r + 2];
            const float rk0 = sRuleU[i*16 +  0 + a];
            const float rk1 = sRuleU[i*16 +  4 + a];
            const float rk2 = sRuleU[i*16 +  8 + a];
            const float rk3 = sRuleU[i*16 + 12 + a];
            float a0 = g[0]*l0 + g[1]*l1 + g[2]*l2;
            float b0, b1, b2, b3;
            bcast4(reduce16(a0), b0, b1, b2, b3);
            tU[i] = fmaf(b0, rk0, fmaf(b1, rk1, fmaf(b2, rk2, b3 * rk3)));
        }

        // ---- outputs: coalesced cached stores, per-u to keep live set low ----
        float* op = out + (size_t)t * 768 + off;
        #pragma unroll
        for (int u = 0; u < 3; ++u) {
            float4 ov = *(const float4*)&sBu[off + 64*u];
            #pragma unroll
            for (int i = 0; i < 4; ++i) {
                const float4 ru = *(const float4*)&sRu[i*192 + 4*r + 64*u];
                ov.x = fmaf(tU[i], ru.x, ov.x);
                ov.y = fmaf(tU[i], ru.y, ov.y);
                ov.z = fmaf(tU[i], ru.z, ov.z);
                ov.w = fmaf(tU[i], ru.w, ov.w);
            }
            *(float4*)(op + 64*u) = ov;
        }

        // ---- rotate prefetch into current ----
        A0 = B0; A1 = B1; A2 = B2;
    }
}

extern "C" void kernel_launch(void* const* d_in, const int* in_sizes, int n_in,
                              void* d_out, int out_size, void* d_ws, size_t ws_size,
                              hipStream_t stream) {
    const float* x      = (const float*)d_in[0];
    const float* rule_d = (const float*)d_in[1];
    const float* Wl_d   = (const float*)d_in[2];
    const float* Wr_d   = (const float*)d_in[3];
    const float* bias_d = (const float*)d_in[4];
    const float* rule_u = (const float*)d_in[5];
    const float* Wl_u   = (const float*)d_in[6];
    const float* Wr_u   = (const float*)d_in[7];
    const float* bias_u = (const float*)d_in[8];
    float* out          = (float*)d_out;

    const int n_tokens = in_sizes[0] / 768;   // 32768

    // 2048 blocks = 8192 waves (8 blocks/CU); 32768 tokens -> 4 tokens/wave.
    const int blocks = (n_tokens + 15) / 16;
    phm_fused<<<dim3(blocks), dim3(256), 0, stream>>>(
        x, rule_d, Wl_d, Wr_d, bias_d, rule_u, Wl_u, Wr_u, bias_u, out, n_tokens);
}